// Round 7
// baseline (31.195 us; speedup 1.0000x reference)
//
#include <hip/hip_runtime.h>

// SDF Chamfer loss, H=W=64, 2 images. TWO kernels, zero atomics, zero fences,
// no global point array: each chamfer block self-extracts candidates+queries.
// ws float layout:
//   [0..3]     int: total masked count per imgset (qblk==0 block of imgset i
//              writes count of set i^1)
//   [64..315]  chamfer partial sums, one per fused block (252)
#define HH 64
#define WW 64
#define NV ((HH-1)*WW)        // 4032
#define NP (NV + HH*(WW-1))   // 8064
#define NQB 63                // query blocks per imgset
#define QPB 128               // query edges per block (63*128 = 8064)
#define EPSF 1e-8f
#define BIGF 3.0e38f
#define PART_OFF 64

__device__ __forceinline__ void edge_point(const float* __restrict__ sdf, int e,
                                           float& R, float& C, bool& m) {
    float v1, v2;
    if (e < NV) {                       // vertical: rows i, i+1
        int i = e >> 6, j = e & 63;
        v1 = sdf[i * WW + j];
        v2 = sdf[i * WW + WW + j];
        float a = fabsf(v1) / (fabsf(v1) + fabsf(v2) + EPSF);
        float frac = (v1 == 0.f) ? 0.f : ((v2 == 0.f) ? 1.f : a);
        R = (float)i + frac; C = (float)j;
    } else {                            // horizontal: cols j, j+1
        int eh = e - NV;
        int i = eh / (WW - 1), j = eh % (WW - 1);
        v1 = sdf[i * WW + j];
        v2 = sdf[i * WW + j + 1];
        float a = fabsf(v1) / (fabsf(v1) + fabsf(v2) + EPSF);
        float frac = (v1 == 0.f) ? 0.f : ((v2 == 0.f) ? 1.f : a);
        R = (float)i; C = (float)j + frac;
    }
    m = (v1 == 0.f) || (v2 == 0.f) || (v1 * v2 < 0.f);
}

// grid: 252 blocks = imgset(4) x qblk(63), 512 threads.
// Self-extracts: full opposite set -> ctile (ballot-compacted, deterministic),
// own 128 query edges -> qpts. Then 64 query slots x 8 threads, 2-pass.
__global__ __launch_bounds__(512) void fused_kernel(const float* __restrict__ pred,
                                                    const float* __restrict__ gt,
                                                    float* __restrict__ ws) {
    int blk = blockIdx.x;
    int imgset = blk / NQB;
    int qblk = blk - imgset * NQB;
    int tid = threadIdx.x, lane = tid & 63, wid = tid >> 6;
    int opp = imgset ^ 1;
    const float* csdf = ((opp & 1) ? gt : pred) + (opp >> 1) * (HH * WW);
    const float* qsdf = ((imgset & 1) ? gt : pred) + (imgset >> 1) * (HH * WW);

    __shared__ __align__(16) float2 ctile[NP + 16];
    __shared__ __align__(16) float2 qpts[QPB];
    __shared__ int wcnt[8];
    __shared__ int qc_s[2];
    unsigned long long lt = (1ull << lane) - 1ull;

    // ---- query extraction + 2-wave ballot compaction (tid < 128) ----
    float QR = 0.f, QC = 0.f; bool qm = false;
    if (tid < QPB) edge_point(qsdf, qblk * QPB + tid, QR, QC, qm);
    unsigned long long qb = __ballot(qm);
    if (tid < QPB && lane == 0) qc_s[wid] = __popcll(qb);
    __syncthreads();
    int qcnt = qc_s[0] + qc_s[1];
    if (qm) qpts[(wid == 1 ? qc_s[0] : 0) + __popcll(qb & lt)] = make_float2(QR, QC);

    // ---- candidate extraction: 16 chunks of 512, block-wide compaction ----
    int ccnt = 0;
    for (int chunk = 0; chunk < 16; ++chunk) {
        int e = (chunk << 9) + tid;
        float R = 0.f, C = 0.f; bool m = false;
        if (e < NP) edge_point(csdf, e, R, C, m);
        unsigned long long b = __ballot(m);
        if (lane == 0) wcnt[wid] = __popcll(b);
        __syncthreads();
        int off = ccnt, tot = 0;
        #pragma unroll
        for (int w = 0; w < 8; ++w) { int c = wcnt[w]; if (w < wid) off += c; tot += c; }
        if (m) ctile[off + __popcll(b & lt)] = make_float2(R, C);
        ccnt += tot;
        __syncthreads();
    }
    int P2 = (ccnt + 31) & ~31;                        // pad to 32 candidates
    for (int i = ccnt + tid; i < P2; i += 512) ctile[i] = make_float2(1e9f, 1e9f);
    if (tid == 0 && qblk == 0) ((int*)ws)[opp] = ccnt;  // publish set-opp count
    __syncthreads();

    // ---- chamfer: 64 slots x 8 threads, 4 indep min chains, 2 passes ----
    int slot = tid >> 3, r = tid & 7;
    const float4* t4 = (const float4*)ctile;
    int kmax = P2 >> 5;
    float acc = 0.f;
    for (int pass = 0; pass < 2; ++pass) {
        if (pass == 1 && qcnt <= 64) break;            // block-uniform
        int q = pass * 64 + slot;
        bool v = q < qcnt;
        float2 qp = v ? qpts[q] : make_float2(1e8f, 1e8f);
        float m0 = BIGF, m1 = BIGF, m2 = BIGF, m3 = BIGF;
        for (int k = 0; k < kmax; ++k) {               // 4 candidates/thread/iter
            float4 a = t4[k * 16 + r];
            float4 c = t4[k * 16 + 8 + r];
            float dx0 = qp.x - a.x, dy0 = qp.y - a.y;
            float dx1 = qp.x - a.z, dy1 = qp.y - a.w;
            float dx2 = qp.x - c.x, dy2 = qp.y - c.y;
            float dx3 = qp.x - c.z, dy3 = qp.y - c.w;
            m0 = fminf(m0, __builtin_fmaf(dx0, dx0, dy0 * dy0));
            m1 = fminf(m1, __builtin_fmaf(dx1, dx1, dy1 * dy1));
            m2 = fminf(m2, __builtin_fmaf(dx2, dx2, dy2 * dy2));
            m3 = fminf(m3, __builtin_fmaf(dx3, dx3, dy3 * dy3));
        }
        float m = fminf(fminf(m0, m1), fminf(m2, m3));
        m = fminf(m, __shfl_xor(m, 1, 64));            // combine 8 r-lanes
        m = fminf(m, __shfl_xor(m, 2, 64));
        m = fminf(m, __shfl_xor(m, 4, 64));
        if (v && r == 0) acc += sqrtf(m);
    }

    // block sum over 512 threads -> one partial
    for (int o = 32; o; o >>= 1) acc += __shfl_down(acc, o, 64);
    __shared__ float red[8];
    if (lane == 0) red[wid] = acc;
    __syncthreads();
    if (tid == 0) {
        float s = 0.f;
        #pragma unroll
        for (int w = 0; w < 8; ++w) s += red[w];
        ws[PART_OFF + blk] = s;
    }
}

// 1 block, 256 threads: combine 252 partials + counts + L1 + final loss.
__global__ __launch_bounds__(256) void tail_kernel(const float* __restrict__ ws,
                                                   const float* __restrict__ pred,
                                                   const float* __restrict__ gt,
                                                   float* __restrict__ out) {
    int tid = threadIdx.x, lane = tid & 63, wid = tid >> 6;
    const int* cnts = (const int*)ws;
    __shared__ float sums[4];
    __shared__ float red[8];

    // chamfer sums: wave w owns imgset w's 63 partials
    float v = (lane < NQB) ? ws[PART_OFF + wid * NQB + lane] : 0.f;
    for (int o = 32; o; o >>= 1) v += __shfl_down(v, o, 64);
    if (lane == 0) sums[wid] = v;

    // L1 from inputs: 2048 float4 spans both images (1024 per image)
    const float4* p4 = (const float4*)pred;
    const float4* g4 = (const float4*)gt;
    float s0 = 0.f, s1 = 0.f;
    #pragma unroll
    for (int j = 0; j < 8; ++j) {
        int idx = tid + j * 256;
        float4 a = p4[idx], b = g4[idx];
        float t = fabsf(a.x - b.x) + fabsf(a.y - b.y) + fabsf(a.z - b.z) + fabsf(a.w - b.w);
        if (j < 4) s0 += t; else s1 += t;
    }
    for (int o = 32; o; o >>= 1) { s0 += __shfl_down(s0, o, 64); s1 += __shfl_down(s1, o, 64); }
    __syncthreads();
    if (lane == 0) { red[wid] = s0; red[4 + wid] = s1; }
    __syncthreads();

    if (tid == 0) {
        float l1a = red[0] + red[1] + red[2] + red[3];
        float l1b = red[4] + red[5] + red[6] + red[7];
        float loss = 0.f;
        for (int b = 0; b < 2; ++b) {
            float mean1 = sums[2 * b + 0] / fmaxf((float)cnts[2 * b + 0], 1.f); // pred->gt
            float mean2 = sums[2 * b + 1] / fmaxf((float)cnts[2 * b + 1], 1.f); // gt->pred
            loss += (b == 0 ? l1a : l1b) * (1.f / (HH * WW)) + fabsf(-mean1 + mean2);
        }
        out[0] = loss * 0.5f;
    }
}

extern "C" void kernel_launch(void* const* d_in, const int* in_sizes, int n_in,
                              void* d_out, int out_size, void* d_ws, size_t ws_size,
                              hipStream_t stream) {
    const float* pred = (const float*)d_in[0];
    const float* gt   = (const float*)d_in[1];
    float* ws  = (float*)d_ws;
    float* out = (float*)d_out;

    hipLaunchKernelGGL(fused_kernel, dim3(4 * NQB), dim3(512), 0, stream, pred, gt, ws);
    hipLaunchKernelGGL(tail_kernel,  dim3(1),       dim3(256), 0, stream, ws, pred, gt, out);
}